// Round 3
// baseline (189.135 us; speedup 1.0000x reference)
//
#include <hip/hip_runtime.h>

#define IMG_H 720
#define IMG_W 1280
#define FX_C 800.0f
#define FY_C 800.0f
#define CX_C 640.0f
#define CY_C 360.0f

// LDS-privatized winner window around the projection center (640, 360).
// sigma_u = sigma_v ~= 11.4 px; +/-48 px = +/-4.2 sigma. Out-of-window points
// (a few hundred) take the direct global-atomic path — correctness does NOT
// depend on the distribution, only performance does.
#define WIN_W 96
#define WIN_H 96
#define WIN_X0 (640 - WIN_W / 2) // 592
#define WIN_Y0 (360 - WIN_H / 2) // 312
#define WIN_PIX (WIN_W * WIN_H)  // 9216 -> 36 KB LDS -> 4 blocks/CU

__global__ __launch_bounds__(256) void scatter_kernel(const float* __restrict__ pos,
                                                      int* __restrict__ winner,
                                                      int n, int per_block) {
    __shared__ int lwin[WIN_PIX];
    for (int j = threadIdx.x; j < WIN_PIX; j += 256) lwin[j] = -1;
    __syncthreads();

    int base = blockIdx.x * per_block;
    int end  = base + per_block;
    if (end > n) end = n;

    #pragma unroll 2
    for (int i = base + (int)threadIdx.x; i < end; i += 256) {
        float x = pos[3 * i + 0];
        float y = pos[3 * i + 1];
        float z = __fadd_rn(pos[3 * i + 2], 3.0f);
        // IEEE-exact, no FMA contraction: must bit-match numpy so floor() agrees
        float u = __fadd_rn(__fmul_rn(FX_C, __fdiv_rn(x, z)), CX_C);
        float v = __fadd_rn(__fmul_rn(FY_C, __fdiv_rn(y, z)), CY_C);
        if (u >= 0.0f && u < (float)IMG_W && v >= 0.0f && v < (float)IMG_H) {
            int xi = (int)floorf(u);
            int yi = (int)floorf(v);
            int wx = xi - WIN_X0;
            int wy = yi - WIN_Y0;
            if ((unsigned)wx < WIN_W && (unsigned)wy < WIN_H) {
                atomicMax(&lwin[wy * WIN_W + wx], i);          // CU-local LDS atomic
            } else {
                atomicMax(&winner[yi * IMG_W + xi], i);        // rare fallback
            }
        }
    }
    __syncthreads();

    // Flush: coalesced window sweep; test-and-skip is safe because winner[]
    // only grows (any stale read is <= true current value).
    for (int j = threadIdx.x; j < WIN_PIX; j += 256) {
        int val = lwin[j];
        if (val >= 0) {
            int wy = j / WIN_W;
            int wx = j - wy * WIN_W;
            int pix = (WIN_Y0 + wy) * IMG_W + (WIN_X0 + wx);
            if (winner[pix] < val)
                atomicMax(&winner[pix], val);
        }
    }
}

// Per-pixel resolve — recompute weight for the winner point
__global__ void resolve_kernel(const float* __restrict__ pos,
                               const float* __restrict__ scales,
                               const float* __restrict__ colors,
                               const int* __restrict__ winner,
                               float* __restrict__ out, int npix) {
    int p = blockIdx.x * blockDim.x + threadIdx.x;
    if (p >= npix) return;
    int w = winner[p];
    float cr = 0.0f, cg = 0.0f, cb = 0.0f;
    if (w >= 0) {
        float x = pos[3 * w + 0];
        float y = pos[3 * w + 1];
        float z = __fadd_rn(pos[3 * w + 2], 3.0f);
        float u = __fadd_rn(__fmul_rn(FX_C, __fdiv_rn(x, z)), CX_C);
        float v = __fadd_rn(__fmul_rn(FY_C, __fdiv_rn(y, z)), CY_C);
        float dx = __fsub_rn(u, floorf(u));
        float dy = __fsub_rn(v, floorf(v));
        float rad = __fmul_rn(scales[3 * w], 100.0f);
        float num = __fadd_rn(__fmul_rn(dx, dx), __fmul_rn(dy, dy));
        float den = __fmul_rn(2.0f, __fmul_rn(rad, rad));
        float wgt = expf(-__fdiv_rn(num, den));
        cr = __fmul_rn(colors[3 * w + 0], wgt);
        cg = __fmul_rn(colors[3 * w + 1], wgt);
        cb = __fmul_rn(colors[3 * w + 2], wgt);
    }
    out[3 * p + 0] = cr;
    out[3 * p + 1] = cg;
    out[3 * p + 2] = cb;
}

extern "C" void kernel_launch(void* const* d_in, const int* in_sizes, int n_in,
                              void* d_out, int out_size, void* d_ws, size_t ws_size,
                              hipStream_t stream) {
    // inputs: [0] camera_poses (unused), [1] positions (N*3), [2] scales (N*3), [3] colors (N*3)
    const float* positions = (const float*)d_in[1];
    const float* scales    = (const float*)d_in[2];
    const float* colors    = (const float*)d_in[3];
    float* out = (float*)d_out;
    int n = in_sizes[1] / 3;
    const int npix = IMG_H * IMG_W;

    int* winner = (int*)d_ws;  // npix int32 = ~3.7 MB scratch

    hipMemsetAsync(winner, 0xFF, (size_t)npix * sizeof(int), stream);

    const int nblocks = 1024;                       // 4 blocks/CU (LDS-limited)
    int per_block = (n + nblocks - 1) / nblocks;
    scatter_kernel<<<nblocks, 256, 0, stream>>>(positions, winner, n, per_block);
    resolve_kernel<<<(npix + 255) / 256, 256, 0, stream>>>(positions, scales, colors,
                                                           winner, out, npix);
}

// Round 4
// 39.715 us; speedup vs baseline: 4.7623x; 4.7623x over previous
//
#include <hip/hip_runtime.h>

#define IMG_H 720
#define IMG_W 1280
#define FX_C 800.0f
#define FY_C 800.0f
#define CX_C 640.0f
#define CY_C 360.0f

// Hot window around the projection center (640, 360).
// sigma_u = sigma_v ~= 11.4 px; +/-48 px ~= +/-4.2 sigma. Out-of-window points
// (a few hundred expected) take a test-and-skip global-atomic path, so
// correctness does NOT depend on the distribution.
#define WIN_W 96
#define WIN_H 96
#define WIN_X0 (640 - WIN_W / 2)  // 592
#define WIN_Y0 (360 - WIN_H / 2)  // 312
#define WIN_PIX (WIN_W * WIN_H)   // 9216
#define LDS_STRIDE 97             // pad: bank index must not be f(wx) only
#define NGROUPS 32

__device__ __forceinline__ void project_point(float x, float y, float zraw,
                                              float& u, float& v) {
    float z = __fadd_rn(zraw, 3.0f);
    // IEEE-exact, no FMA contraction: must bit-match numpy so floor() agrees
    u = __fadd_rn(__fmul_rn(FX_C, __fdiv_rn(x, z)), CX_C);
    v = __fadd_rn(__fmul_rn(FY_C, __fdiv_rn(y, z)), CY_C);
}

__device__ __forceinline__ void splat_one(int i, float x, float y, float zraw,
                                          int* lwin, int* __restrict__ winner) {
    float u, v;
    project_point(x, y, zraw, u, v);
    if (u >= 0.0f && u < (float)IMG_W && v >= 0.0f && v < (float)IMG_H) {
        int xi = (int)floorf(u);
        int yi = (int)floorf(v);
        int wx = xi - WIN_X0;
        int wy = yi - WIN_Y0;
        if ((unsigned)wx < WIN_W && (unsigned)wy < WIN_H) {
            atomicMax(&lwin[wy * LDS_STRIDE + wx], i);     // CU-local, no coherence
        } else {
            int pix = yi * IMG_W + xi;                     // rare fallback
            if (winner[pix] < i) atomicMax(&winner[pix], i);
        }
    }
}

// Pass A: LDS-privatized window, flushed to a PRIVATE global slice (no sharing).
__global__ __launch_bounds__(256) void scatter_win_kernel(
        const float* __restrict__ pos, int* __restrict__ winner,
        int* __restrict__ blockwin, int n, int per_block) {
    __shared__ int lwin[WIN_H * LDS_STRIDE];
    for (int j = threadIdx.x; j < WIN_H * LDS_STRIDE; j += 256) lwin[j] = -1;
    __syncthreads();

    int base = blockIdx.x * per_block;
    int end  = base + per_block;
    if (end > n) end = n;

    for (int i0 = base + (int)threadIdx.x * 4; i0 < end; i0 += 256 * 4) {
        if (i0 + 4 <= end) {
            // 4 points = 48 contiguous bytes = 3 x float4 (16B-aligned since i0%4==0)
            const float4* p4 = (const float4*)(pos + 3 * i0);
            float4 a = p4[0], b = p4[1], c = p4[2];
            splat_one(i0 + 0, a.x, a.y, a.z, lwin, winner);
            splat_one(i0 + 1, a.w, b.x, b.y, lwin, winner);
            splat_one(i0 + 2, b.z, b.w, c.x, lwin, winner);
            splat_one(i0 + 3, c.y, c.z, c.w, lwin, winner);
        } else {
            for (int i = i0; i < end; ++i)
                splat_one(i, pos[3 * i], pos[3 * i + 1], pos[3 * i + 2], lwin, winner);
        }
    }
    __syncthreads();

    int* dst = blockwin + (size_t)blockIdx.x * WIN_PIX;
    for (int j = threadIdx.x; j < WIN_PIX; j += 256) {
        int wy = j / WIN_W;
        int wx = j - wy * WIN_W;
        dst[j] = lwin[wy * LDS_STRIDE + wx];    // coalesced private store
    }
}

// Pass B1: reduce nblocks windows -> NGROUPS partials. grid = (NGROUPS, WIN_PIX/256)
__global__ __launch_bounds__(256) void reduce1_kernel(
        const int* __restrict__ blockwin, int* __restrict__ part2,
        int nblocks, int gsize) {
    int g = blockIdx.x;
    int p = blockIdx.y * 256 + threadIdx.x;
    int b0 = g * gsize;
    int b1 = b0 + gsize; if (b1 > nblocks) b1 = nblocks;
    int m = -1;
    for (int b = b0; b < b1; ++b) {
        int v = blockwin[(size_t)b * WIN_PIX + p];
        m = v > m ? v : m;
    }
    part2[(size_t)g * WIN_PIX + p] = m;
}

// Pass B2: reduce NGROUPS partials -> winner window (single writer per pixel).
__global__ __launch_bounds__(256) void reduce2_kernel(
        const int* __restrict__ part2, int* __restrict__ winner) {
    int p = blockIdx.x * 256 + threadIdx.x;
    if (p >= WIN_PIX) return;
    int m = -1;
    for (int g = 0; g < NGROUPS; ++g) {
        int v = part2[(size_t)g * WIN_PIX + p];
        m = v > m ? v : m;
    }
    int wy = p / WIN_W;
    int wx = p - wy * WIN_W;
    winner[(WIN_Y0 + wy) * IMG_W + (WIN_X0 + wx)] = m;  // disjoint from fallback atomics
}

// Fallback scatter (round-2 style) if workspace is too small.
__global__ void scatter_simple_kernel(const float* __restrict__ pos,
                                      int* __restrict__ winner, int n) {
    int gid = blockIdx.x * blockDim.x + threadIdx.x;
    if (gid >= n) return;
    int i = n - 1 - gid;
    float u, v;
    project_point(pos[3 * i], pos[3 * i + 1], pos[3 * i + 2], u, v);
    if (u >= 0.0f && u < (float)IMG_W && v >= 0.0f && v < (float)IMG_H) {
        int pix = (int)floorf(v) * IMG_W + (int)floorf(u);
        if (winner[pix] < i) atomicMax(&winner[pix], i);
    }
}

// Resolve: recompute winner point's weight, write HWC image.
__global__ void resolve_kernel(const float* __restrict__ pos,
                               const float* __restrict__ scales,
                               const float* __restrict__ colors,
                               const int* __restrict__ winner,
                               float* __restrict__ out, int npix) {
    int p = blockIdx.x * blockDim.x + threadIdx.x;
    if (p >= npix) return;
    int w = winner[p];
    float cr = 0.0f, cg = 0.0f, cb = 0.0f;
    if (w >= 0) {
        float u, v;
        project_point(pos[3 * w], pos[3 * w + 1], pos[3 * w + 2], u, v);
        float dx = __fsub_rn(u, floorf(u));
        float dy = __fsub_rn(v, floorf(v));
        float rad = __fmul_rn(scales[3 * w], 100.0f);
        float num = __fadd_rn(__fmul_rn(dx, dx), __fmul_rn(dy, dy));
        float den = __fmul_rn(2.0f, __fmul_rn(rad, rad));
        float wgt = expf(-__fdiv_rn(num, den));
        cr = __fmul_rn(colors[3 * w + 0], wgt);
        cg = __fmul_rn(colors[3 * w + 1], wgt);
        cb = __fmul_rn(colors[3 * w + 2], wgt);
    }
    out[3 * p + 0] = cr;
    out[3 * p + 1] = cg;
    out[3 * p + 2] = cb;
}

extern "C" void kernel_launch(void* const* d_in, const int* in_sizes, int n_in,
                              void* d_out, int out_size, void* d_ws, size_t ws_size,
                              hipStream_t stream) {
    // inputs: [0] camera_poses (unused), [1] positions, [2] scales, [3] colors
    const float* positions = (const float*)d_in[1];
    const float* scales    = (const float*)d_in[2];
    const float* colors    = (const float*)d_in[3];
    float* out = (float*)d_out;
    int n = in_sizes[1] / 3;
    const int npix = IMG_H * IMG_W;

    const size_t winner_bytes = (size_t)npix * sizeof(int);
    const size_t part2_bytes  = (size_t)NGROUPS * WIN_PIX * sizeof(int);
    const size_t slice_bytes  = (size_t)WIN_PIX * sizeof(int);

    int* winner = (int*)d_ws;
    hipMemsetAsync(winner, 0xFF, winner_bytes, stream);

    // adaptive block count from available scratch
    long long avail = (long long)ws_size - (long long)winner_bytes - (long long)part2_bytes;
    int nblocks = (avail > 0) ? (int)(avail / (long long)slice_bytes) : 0;
    if (nblocks > 1024) nblocks = 1024;

    if (nblocks >= 128) {
        int* blockwin = (int*)((char*)d_ws + winner_bytes + part2_bytes);
        int* part2    = (int*)((char*)d_ws + winner_bytes);
        int per_block = ((n + nblocks - 1) / nblocks + 3) & ~3;  // multiple of 4
        int gsize = (nblocks + NGROUPS - 1) / NGROUPS;

        scatter_win_kernel<<<nblocks, 256, 0, stream>>>(positions, winner, blockwin,
                                                        n, per_block);
        dim3 g1(NGROUPS, WIN_PIX / 256);
        reduce1_kernel<<<g1, 256, 0, stream>>>(blockwin, part2, nblocks, gsize);
        reduce2_kernel<<<(WIN_PIX + 255) / 256, 256, 0, stream>>>(part2, winner);
    } else {
        scatter_simple_kernel<<<(n + 255) / 256, 256, 0, stream>>>(positions, winner, n);
    }

    resolve_kernel<<<(npix + 255) / 256, 256, 0, stream>>>(positions, scales, colors,
                                                           winner, out, npix);
}

// Round 5
// 39.479 us; speedup vs baseline: 4.7908x; 1.0060x over previous
//
#include <hip/hip_runtime.h>

#define IMG_H 720
#define IMG_W 1280
#define FX_C 800.0f
#define FY_C 800.0f
#define CX_C 640.0f
#define CY_C 360.0f

// Hot window around the projection center (640, 360).
// sigma_u = sigma_v ~= 11.4 px; +/-48 px ~= +/-4.2 sigma. Out-of-window points
// (a few hundred expected) take a test-and-skip global-atomic path, so
// correctness does NOT depend on the distribution.
#define WIN_W 96
#define WIN_H 96
#define WIN_X0 (640 - WIN_W / 2)  // 592
#define WIN_Y0 (360 - WIN_H / 2)  // 312
#define WIN_PIX (WIN_W * WIN_H)   // 9216
#define LDS_STRIDE 97             // pad: bank index must not be f(wx) only
#define NGROUPS 32

// Fast winner init: grid-strided int4 stores of -1 (rocclr fillBuffer is ~39us!)
__global__ __launch_bounds__(256) void init_winner_kernel(int4* __restrict__ winner4,
                                                          int nquads) {
    int stride = gridDim.x * blockDim.x;
    for (int i = blockIdx.x * blockDim.x + threadIdx.x; i < nquads; i += stride)
        winner4[i] = make_int4(-1, -1, -1, -1);
}

__device__ __forceinline__ void project_point(float x, float y, float zraw,
                                              float& u, float& v) {
    float z = __fadd_rn(zraw, 3.0f);
    // IEEE-exact, no FMA contraction: must bit-match numpy so floor() agrees
    u = __fadd_rn(__fmul_rn(FX_C, __fdiv_rn(x, z)), CX_C);
    v = __fadd_rn(__fmul_rn(FY_C, __fdiv_rn(y, z)), CY_C);
}

__device__ __forceinline__ void splat_one(int i, float x, float y, float zraw,
                                          int* lwin, int* __restrict__ winner) {
    float u, v;
    project_point(x, y, zraw, u, v);
    if (u >= 0.0f && u < (float)IMG_W && v >= 0.0f && v < (float)IMG_H) {
        int xi = (int)floorf(u);
        int yi = (int)floorf(v);
        int wx = xi - WIN_X0;
        int wy = yi - WIN_Y0;
        if ((unsigned)wx < WIN_W && (unsigned)wy < WIN_H) {
            atomicMax(&lwin[wy * LDS_STRIDE + wx], i);     // CU-local, no coherence
        } else {
            int pix = yi * IMG_W + xi;                     // rare fallback
            if (winner[pix] < i) atomicMax(&winner[pix], i);
        }
    }
}

// Pass A: LDS-privatized window, flushed to a PRIVATE global slice (no sharing).
__global__ __launch_bounds__(256) void scatter_win_kernel(
        const float* __restrict__ pos, int* __restrict__ winner,
        int* __restrict__ blockwin, int n, int per_block) {
    __shared__ int lwin[WIN_H * LDS_STRIDE];
    for (int j = threadIdx.x; j < WIN_H * LDS_STRIDE; j += 256) lwin[j] = -1;
    __syncthreads();

    int base = blockIdx.x * per_block;
    int end  = base + per_block;
    if (end > n) end = n;

    for (int i0 = base + (int)threadIdx.x * 4; i0 < end; i0 += 256 * 4) {
        if (i0 + 4 <= end) {
            // 4 points = 48 contiguous bytes = 3 x float4 (16B-aligned since i0%4==0)
            const float4* p4 = (const float4*)(pos + 3 * i0);
            float4 a = p4[0], b = p4[1], c = p4[2];
            splat_one(i0 + 0, a.x, a.y, a.z, lwin, winner);
            splat_one(i0 + 1, a.w, b.x, b.y, lwin, winner);
            splat_one(i0 + 2, b.z, b.w, c.x, lwin, winner);
            splat_one(i0 + 3, c.y, c.z, c.w, lwin, winner);
        } else {
            for (int i = i0; i < end; ++i)
                splat_one(i, pos[3 * i], pos[3 * i + 1], pos[3 * i + 2], lwin, winner);
        }
    }
    __syncthreads();

    int* dst = blockwin + (size_t)blockIdx.x * WIN_PIX;
    for (int j = threadIdx.x; j < WIN_PIX; j += 256) {
        int wy = j / WIN_W;
        int wx = j - wy * WIN_W;
        dst[j] = lwin[wy * LDS_STRIDE + wx];    // coalesced private store
    }
}

// Pass B1: reduce nblocks windows -> NGROUPS partials. grid = (NGROUPS, WIN_PIX/256)
__global__ __launch_bounds__(256) void reduce1_kernel(
        const int* __restrict__ blockwin, int* __restrict__ part2,
        int nblocks, int gsize) {
    int g = blockIdx.x;
    int p = blockIdx.y * 256 + threadIdx.x;
    int b0 = g * gsize;
    int b1 = b0 + gsize; if (b1 > nblocks) b1 = nblocks;
    int m = -1;
    for (int b = b0; b < b1; ++b) {
        int v = blockwin[(size_t)b * WIN_PIX + p];
        m = v > m ? v : m;
    }
    part2[(size_t)g * WIN_PIX + p] = m;
}

// Pass B2: reduce NGROUPS partials -> winner window (single writer per pixel).
__global__ __launch_bounds__(256) void reduce2_kernel(
        const int* __restrict__ part2, int* __restrict__ winner) {
    int p = blockIdx.x * 256 + threadIdx.x;
    if (p >= WIN_PIX) return;
    int m = -1;
    for (int g = 0; g < NGROUPS; ++g) {
        int v = part2[(size_t)g * WIN_PIX + p];
        m = v > m ? v : m;
    }
    int wy = p / WIN_W;
    int wx = p - wy * WIN_W;
    winner[(WIN_Y0 + wy) * IMG_W + (WIN_X0 + wx)] = m;  // disjoint from fallback atomics
}

// Fallback scatter (round-2 style) if workspace is too small.
__global__ void scatter_simple_kernel(const float* __restrict__ pos,
                                      int* __restrict__ winner, int n) {
    int gid = blockIdx.x * blockDim.x + threadIdx.x;
    if (gid >= n) return;
    int i = n - 1 - gid;
    float u, v;
    project_point(pos[3 * i], pos[3 * i + 1], pos[3 * i + 2], u, v);
    if (u >= 0.0f && u < (float)IMG_W && v >= 0.0f && v < (float)IMG_H) {
        int pix = (int)floorf(v) * IMG_W + (int)floorf(u);
        if (winner[pix] < i) atomicMax(&winner[pix], i);
    }
}

// Resolve: recompute winner point's weight, write HWC image.
__global__ void resolve_kernel(const float* __restrict__ pos,
                               const float* __restrict__ scales,
                               const float* __restrict__ colors,
                               const int* __restrict__ winner,
                               float* __restrict__ out, int npix) {
    int p = blockIdx.x * blockDim.x + threadIdx.x;
    if (p >= npix) return;
    int w = winner[p];
    float cr = 0.0f, cg = 0.0f, cb = 0.0f;
    if (w >= 0) {
        float u, v;
        project_point(pos[3 * w], pos[3 * w + 1], pos[3 * w + 2], u, v);
        float dx = __fsub_rn(u, floorf(u));
        float dy = __fsub_rn(v, floorf(v));
        float rad = __fmul_rn(scales[3 * w], 100.0f);
        float num = __fadd_rn(__fmul_rn(dx, dx), __fmul_rn(dy, dy));
        float den = __fmul_rn(2.0f, __fmul_rn(rad, rad));
        float wgt = expf(-__fdiv_rn(num, den));
        cr = __fmul_rn(colors[3 * w + 0], wgt);
        cg = __fmul_rn(colors[3 * w + 1], wgt);
        cb = __fmul_rn(colors[3 * w + 2], wgt);
    }
    out[3 * p + 0] = cr;
    out[3 * p + 1] = cg;
    out[3 * p + 2] = cb;
}

extern "C" void kernel_launch(void* const* d_in, const int* in_sizes, int n_in,
                              void* d_out, int out_size, void* d_ws, size_t ws_size,
                              hipStream_t stream) {
    // inputs: [0] camera_poses (unused), [1] positions, [2] scales, [3] colors
    const float* positions = (const float*)d_in[1];
    const float* scales    = (const float*)d_in[2];
    const float* colors    = (const float*)d_in[3];
    float* out = (float*)d_out;
    int n = in_sizes[1] / 3;
    const int npix = IMG_H * IMG_W;

    const size_t winner_bytes = (size_t)npix * sizeof(int);
    const size_t part2_bytes  = (size_t)NGROUPS * WIN_PIX * sizeof(int);
    const size_t slice_bytes  = (size_t)WIN_PIX * sizeof(int);

    int* winner = (int*)d_ws;

    // npix = 921600, divisible by 4 -> 230400 int4 quads
    int nquads = npix / 4;
    init_winner_kernel<<<900, 256, 0, stream>>>((int4*)winner, nquads);

    // adaptive block count from available scratch
    long long avail = (long long)ws_size - (long long)winner_bytes - (long long)part2_bytes;
    int nblocks = (avail > 0) ? (int)(avail / (long long)slice_bytes) : 0;
    if (nblocks > 1024) nblocks = 1024;

    if (nblocks >= 128) {
        int* blockwin = (int*)((char*)d_ws + winner_bytes + part2_bytes);
        int* part2    = (int*)((char*)d_ws + winner_bytes);
        int per_block = ((n + nblocks - 1) / nblocks + 3) & ~3;  // multiple of 4
        int gsize = (nblocks + NGROUPS - 1) / NGROUPS;

        scatter_win_kernel<<<nblocks, 256, 0, stream>>>(positions, winner, blockwin,
                                                        n, per_block);
        dim3 g1(NGROUPS, WIN_PIX / 256);
        reduce1_kernel<<<g1, 256, 0, stream>>>(blockwin, part2, nblocks, gsize);
        reduce2_kernel<<<(WIN_PIX + 255) / 256, 256, 0, stream>>>(part2, winner);
    } else {
        scatter_simple_kernel<<<(n + 255) / 256, 256, 0, stream>>>(positions, winner, n);
    }

    resolve_kernel<<<(npix + 255) / 256, 256, 0, stream>>>(positions, scales, colors,
                                                           winner, out, npix);
}

// Round 6
// 30.854 us; speedup vs baseline: 6.1300x; 1.2795x over previous
//
#include <hip/hip_runtime.h>

#define IMG_H 720
#define IMG_W 1280
#define FX_C 800.0f
#define FY_C 800.0f
#define CX_C 640.0f
#define CY_C 360.0f

// Hot window around the projection center (640, 360).
// sigma_u = sigma_v ~= 11.4 px; +/-48 px ~= +/-4.2 sigma. Out-of-window points
// (~200 expected) take a test-and-skip global-atomic path, so correctness does
// NOT depend on the distribution.
#define WIN_W 96
#define WIN_H 96
#define WIN_X0 (640 - WIN_W / 2)  // 592
#define WIN_Y0 (360 - WIN_H / 2)  // 312
#define WIN_PIX (WIN_W * WIN_H)   // 9216
#define LDS_STRIDE 97             // pad: bank index must not be f(wx) only
#define NGROUPS 32
#define SCAT_BLOCKS 256           // 1 block/CU, 8 waves/CU
#define SCAT_THREADS 512

// Fast winner init: grid-strided int4 stores of -1
__global__ __launch_bounds__(256) void init_winner_kernel(int4* __restrict__ winner4,
                                                          int nquads) {
    int stride = gridDim.x * blockDim.x;
    for (int i = blockIdx.x * blockDim.x + threadIdx.x; i < nquads; i += stride)
        winner4[i] = make_int4(-1, -1, -1, -1);
}

__device__ __forceinline__ void project_point(float x, float y, float zraw,
                                              float& u, float& v) {
    float z = __fadd_rn(zraw, 3.0f);
    // IEEE-exact, no FMA contraction: must bit-match numpy so floor() agrees
    u = __fadd_rn(__fmul_rn(FX_C, __fdiv_rn(x, z)), CX_C);
    v = __fadd_rn(__fmul_rn(FY_C, __fdiv_rn(y, z)), CY_C);
}

__device__ __forceinline__ void splat_one(int i, float x, float y, float zraw,
                                          int* lwin, int* __restrict__ winner) {
    float u, v;
    project_point(x, y, zraw, u, v);
    if (u >= 0.0f && u < (float)IMG_W && v >= 0.0f && v < (float)IMG_H) {
        int xi = (int)floorf(u);
        int yi = (int)floorf(v);
        int wx = xi - WIN_X0;
        int wy = yi - WIN_Y0;
        if ((unsigned)wx < WIN_W && (unsigned)wy < WIN_H) {
            atomicMax(&lwin[wy * LDS_STRIDE + wx], i);     // CU-local, no coherence
        } else {
            int pix = yi * IMG_W + xi;                     // rare fallback
            if (winner[pix] < i) atomicMax(&winner[pix], i);
        }
    }
}

// Pass A: LDS-privatized window, flushed to a PRIVATE global slice (no sharing).
__global__ __launch_bounds__(SCAT_THREADS) void scatter_win_kernel(
        const float* __restrict__ pos, int* __restrict__ winner,
        int* __restrict__ blockwin, int n, int per_block) {
    __shared__ int lwin[WIN_H * LDS_STRIDE];
    for (int j = threadIdx.x; j < WIN_H * LDS_STRIDE; j += SCAT_THREADS) lwin[j] = -1;
    __syncthreads();

    int base = blockIdx.x * per_block;
    int end  = base + per_block;
    if (end > n) end = n;

    #pragma unroll 2
    for (int i0 = base + (int)threadIdx.x * 4; i0 < end; i0 += SCAT_THREADS * 4) {
        if (i0 + 4 <= end) {
            // 4 points = 48 contiguous bytes = 3 x float4 (16B-aligned since i0%4==0)
            const float4* p4 = (const float4*)(pos + 3 * i0);
            float4 a = p4[0], b = p4[1], c = p4[2];
            splat_one(i0 + 0, a.x, a.y, a.z, lwin, winner);
            splat_one(i0 + 1, a.w, b.x, b.y, lwin, winner);
            splat_one(i0 + 2, b.z, b.w, c.x, lwin, winner);
            splat_one(i0 + 3, c.y, c.z, c.w, lwin, winner);
        } else {
            for (int i = i0; i < end; ++i)
                splat_one(i, pos[3 * i], pos[3 * i + 1], pos[3 * i + 2], lwin, winner);
        }
    }
    __syncthreads();

    int* dst = blockwin + (size_t)blockIdx.x * WIN_PIX;
    for (int j = threadIdx.x; j < WIN_PIX; j += SCAT_THREADS) {
        int wy = j / WIN_W;
        int wx = j - wy * WIN_W;
        dst[j] = lwin[wy * LDS_STRIDE + wx];    // coalesced private store
    }
}

// Pass B1: reduce nblocks windows -> NGROUPS partials. grid = (NGROUPS, WIN_PIX/256)
__global__ __launch_bounds__(256) void reduce1_kernel(
        const int* __restrict__ blockwin, int* __restrict__ part2,
        int nblocks, int gsize) {
    int g = blockIdx.x;
    int p = blockIdx.y * 256 + threadIdx.x;
    int b0 = g * gsize;
    int b1 = b0 + gsize; if (b1 > nblocks) b1 = nblocks;
    int m = -1;
    for (int b = b0; b < b1; ++b) {
        int v = blockwin[(size_t)b * WIN_PIX + p];
        m = v > m ? v : m;
    }
    part2[(size_t)g * WIN_PIX + p] = m;
}

// Fallback scatter (round-2 style) if workspace is too small.
__global__ void scatter_simple_kernel(const float* __restrict__ pos,
                                      int* __restrict__ winner, int n) {
    int gid = blockIdx.x * blockDim.x + threadIdx.x;
    if (gid >= n) return;
    int i = n - 1 - gid;
    float u, v;
    project_point(pos[3 * i], pos[3 * i + 1], pos[3 * i + 2], u, v);
    if (u >= 0.0f && u < (float)IMG_W && v >= 0.0f && v < (float)IMG_H) {
        int pix = (int)floorf(v) * IMG_W + (int)floorf(u);
        if (winner[pix] < i) atomicMax(&winner[pix], i);
    }
}

// Resolve: window pixels take max over NGROUPS partials (fused reduce2);
// others read winner[]. Then recompute the winner point's weight, write HWC.
__global__ __launch_bounds__(256) void resolve_kernel(
        const float* __restrict__ pos, const float* __restrict__ scales,
        const float* __restrict__ colors, const int* __restrict__ part2,
        const int* __restrict__ winner, float* __restrict__ out,
        int npix, int use_part2) {
    int p = blockIdx.x * blockDim.x + threadIdx.x;
    if (p >= npix) return;
    int py = p / IMG_W;
    int px = p - py * IMG_W;
    int wx = px - WIN_X0;
    int wy = py - WIN_Y0;
    int w;
    if (use_part2 && (unsigned)wx < WIN_W && (unsigned)wy < WIN_H) {
        int wp = wy * WIN_W + wx;
        int m = -1;
        #pragma unroll
        for (int g = 0; g < NGROUPS; ++g) {
            int v = part2[g * WIN_PIX + wp];
            m = v > m ? v : m;
        }
        w = m;
    } else {
        w = winner[p];
    }
    float cr = 0.0f, cg = 0.0f, cb = 0.0f;
    if (w >= 0) {
        float u, v;
        project_point(pos[3 * w], pos[3 * w + 1], pos[3 * w + 2], u, v);
        float dx = __fsub_rn(u, floorf(u));
        float dy = __fsub_rn(v, floorf(v));
        float rad = __fmul_rn(scales[3 * w], 100.0f);
        float num = __fadd_rn(__fmul_rn(dx, dx), __fmul_rn(dy, dy));
        float den = __fmul_rn(2.0f, __fmul_rn(rad, rad));
        float wgt = expf(-__fdiv_rn(num, den));
        cr = __fmul_rn(colors[3 * w + 0], wgt);
        cg = __fmul_rn(colors[3 * w + 1], wgt);
        cb = __fmul_rn(colors[3 * w + 2], wgt);
    }
    out[3 * p + 0] = cr;
    out[3 * p + 1] = cg;
    out[3 * p + 2] = cb;
}

extern "C" void kernel_launch(void* const* d_in, const int* in_sizes, int n_in,
                              void* d_out, int out_size, void* d_ws, size_t ws_size,
                              hipStream_t stream) {
    // inputs: [0] camera_poses (unused), [1] positions, [2] scales, [3] colors
    const float* positions = (const float*)d_in[1];
    const float* scales    = (const float*)d_in[2];
    const float* colors    = (const float*)d_in[3];
    float* out = (float*)d_out;
    int n = in_sizes[1] / 3;
    const int npix = IMG_H * IMG_W;

    const size_t winner_bytes = (size_t)npix * sizeof(int);
    const size_t part2_bytes  = (size_t)NGROUPS * WIN_PIX * sizeof(int);
    const size_t slice_bytes  = (size_t)WIN_PIX * sizeof(int);

    int* winner = (int*)d_ws;

    // npix = 921600, divisible by 4 -> 230400 int4 quads
    init_winner_kernel<<<900, 256, 0, stream>>>((int4*)winner, npix / 4);

    // adaptive block count from available scratch
    long long avail = (long long)ws_size - (long long)winner_bytes - (long long)part2_bytes;
    int nblocks = (avail > 0) ? (int)(avail / (long long)slice_bytes) : 0;
    if (nblocks > SCAT_BLOCKS) nblocks = SCAT_BLOCKS;

    if (nblocks >= 128) {
        int* part2    = (int*)((char*)d_ws + winner_bytes);
        int* blockwin = (int*)((char*)d_ws + winner_bytes + part2_bytes);
        int per_block = ((n + nblocks - 1) / nblocks + 3) & ~3;  // multiple of 4
        int gsize = (nblocks + NGROUPS - 1) / NGROUPS;

        scatter_win_kernel<<<nblocks, SCAT_THREADS, 0, stream>>>(positions, winner,
                                                                 blockwin, n, per_block);
        dim3 g1(NGROUPS, WIN_PIX / 256);
        reduce1_kernel<<<g1, 256, 0, stream>>>(blockwin, part2, nblocks, gsize);
        resolve_kernel<<<(npix + 255) / 256, 256, 0, stream>>>(
            positions, scales, colors, part2, winner, out, npix, 1);
    } else {
        scatter_simple_kernel<<<(n + 255) / 256, 256, 0, stream>>>(positions, winner, n);
        resolve_kernel<<<(npix + 255) / 256, 256, 0, stream>>>(
            positions, scales, colors, (const int*)d_ws /*unused*/, winner, out, npix, 0);
    }
}